// Round 11
// baseline (749.602 us; speedup 1.0000x reference)
//
#include <hip/hip_runtime.h>
#include <stdint.h>

#define N_NODES 100000
#define N_EDGES 600000
#define DMODEL  128
#define NLAYERS 4
#define NGRAPH  128
#define NCLASS  10
#define BN_EPS  1e-5f
#define NSLOT   32     // stat partial slots (atomic contention spreading)

typedef __bf16 bf16x8 __attribute__((ext_vector_type(8)));
typedef __bf16 bf16x4 __attribute__((ext_vector_type(4)));
typedef __bf16 bf16x2 __attribute__((ext_vector_type(2)));
typedef float  f32x4  __attribute__((ext_vector_type(4)));

// ------- init: zero accumulators, transpose+split weights, graph boundaries -------
__global__ void k_init(int* __restrict__ deg, float* __restrict__ statpart,
                       float* __restrict__ psum,
                       const float* __restrict__ w1, const float* __restrict__ w2,
                       __bf16* __restrict__ wt_hi, __bf16* __restrict__ wt_lo,
                       const int* __restrict__ batch, int* __restrict__ gstart) {
  int i = blockIdx.x * 256 + threadIdx.x;   // grid 512*256 = 131072
  if (i < N_NODES) deg[i] = 0;
  if (i < NSLOT * 2 * DMODEL) statpart[i] = 0.0f;
  if (i < NGRAPH * DMODEL) psum[i] = 0.0f;
  // weight transpose + hi/lo split: wt[mat][n][k] = split(w[mat][k][n])
  {
    int mat = i >> 14;
    int rem = i & 16383;
    int n = rem >> 7;
    int k = rem & 127;
    int l = mat >> 1;
    int which = mat & 1;
    const float* w = which ? w2 : w1;
    float v = w[(size_t)l * DMODEL * DMODEL + (size_t)k * DMODEL + n];
    __bf16 hi = (__bf16)v;
    wt_hi[i] = hi;
    wt_lo[i] = (__bf16)(v - (float)hi);
  }
  // graph boundaries by binary search over sorted batch
  if (i <= NGRAPH) {
    int lo = 0;
    int hi = N_NODES;
    while (lo < hi) {
      int mid = (lo + hi) >> 1;
      if (batch[mid] < i) lo = mid + 1; else hi = mid;
    }
    gstart[i] = lo;
  }
}

// ---------------- embedding gather: h[i,d] = bf16(emb[x[i],d]) ----------------
__global__ void k_embed(const int* __restrict__ x, const float* __restrict__ emb,
                        __bf16* __restrict__ h) {
  int idx = blockIdx.x * 256 + threadIdx.x;        // over N*D/2
  if (idx >= N_NODES * DMODEL / 2) return;
  int i = idx >> 6;
  int p = idx & 63;
  float2 v = *(const float2*)(emb + (size_t)x[i] * DMODEL + p * 2);
  bf16x2 o;
  o[0] = (__bf16)v.x;
  o[1] = (__bf16)v.y;
  *(bf16x2*)(h + (size_t)i * DMODEL + p * 2) = o;
}

// ---------------- CSR build ----------------
__global__ void k_hist(const int* __restrict__ dst, int* __restrict__ deg) {
  int e = blockIdx.x * 256 + threadIdx.x;
  if (e < N_EDGES) atomicAdd(&deg[dst[e]], 1);
}

__global__ void k_scan1(const int* __restrict__ deg, int* __restrict__ out,
                        int* __restrict__ bsum, int n) {
  __shared__ int lds[256];
  int t = threadIdx.x;
  int idx = blockIdx.x * 256 + t;
  int v = (idx < n) ? deg[idx] : 0;
  int val = v;
  lds[t] = val;
  for (int ofs = 1; ofs < 256; ofs <<= 1) {
    __syncthreads();
    int u = (t >= ofs) ? lds[t - ofs] : 0;
    __syncthreads();
    val += u;
    lds[t] = val;
  }
  if (idx < n) out[idx] = val - v;           // exclusive within chunk
  if (t == 255) bsum[blockIdx.x] = val;      // chunk total
}

__global__ void k_scan2(const int* __restrict__ bsum, int* __restrict__ bsumx, int nb) {
  __shared__ int lds[512];
  int t = threadIdx.x;
  int v = (t < nb) ? bsum[t] : 0;
  int val = v;
  lds[t] = val;
  for (int ofs = 1; ofs < 512; ofs <<= 1) {
    __syncthreads();
    int u = (t >= ofs) ? lds[t - ofs] : 0;
    __syncthreads();
    val += u;
    lds[t] = val;
  }
  if (t < nb) bsumx[t] = val - v;
}

__global__ void k_scan3(int* __restrict__ row_start, int* __restrict__ cursor,
                        const int* __restrict__ bsumx, int n, int total) {
  int idx = blockIdx.x * 256 + threadIdx.x;
  if (idx < n) {
    int v = row_start[idx] + bsumx[blockIdx.x];
    row_start[idx] = v;
    cursor[idx] = v;
  }
  if (idx == 0) row_start[n] = total;
}

// pack each edge as 16B {src, a0, a1, pad} at its CSR slot
__global__ void k_scatter(const int* __restrict__ ei, const float* __restrict__ ea,
                          int* __restrict__ cursor, int4* __restrict__ epack) {
  int e = blockIdx.x * 256 + threadIdx.x;
  if (e >= N_EDGES) return;
  int s = ei[e];
  int d = ei[N_EDGES + e];
  int pos = atomicAdd(&cursor[d], 1);
  int4 pk;
  pk.x = s;
  pk.y = __float_as_int(ea[2 * e]);
  pk.z = __float_as_int(ea[2 * e + 1]);
  pk.w = 0;
  epack[pos] = pk;
}

// ------- message + aggregate: z = act(h_i) + sum_in relu(act(h_src) + edge_lin) -----
// act(h) = relu(s*h + t) when hasT (deferred BN+relu of previous layer), else identity.
// HALF-WAVE per node: 32 lanes x 4 channels (bf16x4 8B gathers), 2 nodes/wave,
// 8 nodes/block. Unchanged from round 10 (two arrangements measured identical:
// gather-latency floor ~55 us at this locality).
__global__ void __launch_bounds__(256) k_agg(
    const __bf16* __restrict__ h, const int* __restrict__ row_start,
    const int4* __restrict__ epack,
    const float* __restrict__ ew,   // edge_w + l*2*D, layout [2][D]
    const float* __restrict__ ebp,  // edge_b + l*D
    const float* __restrict__ sIn, const float* __restrict__ tIn, int hasT,
    __bf16* __restrict__ z) {
  int node = blockIdx.x * 8 + (threadIdx.x >> 5);
  int ln = threadIdx.x & 31;
  int d0 = ln * 4;

  float4 ew0 = *(const float4*)(ew + d0);
  float4 ew1 = *(const float4*)(ew + DMODEL + d0);
  float4 eb  = *(const float4*)(ebp + d0);
  float4 s4;
  float4 t4;
  if (hasT) {
    s4 = *(const float4*)(sIn + d0);
    t4 = *(const float4*)(tIn + d0);
  }

  bf16x4 hv = *(const bf16x4*)(h + (size_t)node * DMODEL + d0);
  float acc0, acc1, acc2, acc3;
  {
    float r0 = (float)hv[0];
    float r1 = (float)hv[1];
    float r2 = (float)hv[2];
    float r3 = (float)hv[3];
    if (hasT) {
      acc0 = fmaxf(s4.x * r0 + t4.x, 0.0f);
      acc1 = fmaxf(s4.y * r1 + t4.y, 0.0f);
      acc2 = fmaxf(s4.z * r2 + t4.z, 0.0f);
      acc3 = fmaxf(s4.w * r3 + t4.w, 0.0f);
    } else {
      acc0 = r0; acc1 = r1; acc2 = r2; acc3 = r3;
    }
  }

  int j0 = row_start[node];
  int j1 = row_start[node + 1];
  int j = j0;

#define AGG_ONE(E, V)                                                          \
  {                                                                            \
    float a0 = __int_as_float((E).y);                                          \
    float a1 = __int_as_float((E).z);                                          \
    float f0 = (float)(V)[0];                                                  \
    float f1 = (float)(V)[1];                                                  \
    float f2 = (float)(V)[2];                                                  \
    float f3 = (float)(V)[3];                                                  \
    if (hasT) {                                                                \
      f0 = fmaxf(s4.x * f0 + t4.x, 0.0f);                                      \
      f1 = fmaxf(s4.y * f1 + t4.y, 0.0f);                                      \
      f2 = fmaxf(s4.z * f2 + t4.z, 0.0f);                                      \
      f3 = fmaxf(s4.w * f3 + t4.w, 0.0f);                                      \
    }                                                                          \
    acc0 += fmaxf(f0 + a0 * ew0.x + a1 * ew1.x + eb.x, 0.0f);                  \
    acc1 += fmaxf(f1 + a0 * ew0.y + a1 * ew1.y + eb.y, 0.0f);                  \
    acc2 += fmaxf(f2 + a0 * ew0.z + a1 * ew1.z + eb.z, 0.0f);                  \
    acc3 += fmaxf(f3 + a0 * ew0.w + a1 * ew1.w + eb.w, 0.0f);                  \
  }

  for (; j + 4 <= j1; j += 4) {
    int4 e0 = epack[j];
    int4 e1 = epack[j + 1];
    int4 e2 = epack[j + 2];
    int4 e3 = epack[j + 3];
    bf16x4 v0 = *(const bf16x4*)(h + (size_t)e0.x * DMODEL + d0);
    bf16x4 v1 = *(const bf16x4*)(h + (size_t)e1.x * DMODEL + d0);
    bf16x4 v2 = *(const bf16x4*)(h + (size_t)e2.x * DMODEL + d0);
    bf16x4 v3 = *(const bf16x4*)(h + (size_t)e3.x * DMODEL + d0);
    AGG_ONE(e0, v0)
    AGG_ONE(e1, v1)
    AGG_ONE(e2, v2)
    AGG_ONE(e3, v3)
  }
  for (; j < j1; ++j) {
    int4 e0 = epack[j];
    bf16x4 v0 = *(const bf16x4*)(h + (size_t)e0.x * DMODEL + d0);
    AGG_ONE(e0, v0)
  }
#undef AGG_ONE

  bf16x4 o;
  o[0] = (__bf16)acc0;
  o[1] = (__bf16)acc1;
  o[2] = (__bf16)acc2;
  o[3] = (__bf16)acc3;
  *(bf16x4*)(z + (size_t)node * DMODEL + d0) = o;
}

// ---------------- GEMM: Y = act(X) @ W + bias  (bf16 MFMA, split-W, register-B) -----
// Round-7 structure with 16-ROW chunks (was 32): A frags 32->16 VGPRs, total ~115
// -> 4 waves/SIMD (vs 3 at VGPR 148) and 2x finer chunk interleave. No barriers,
// no fences, no prefetch buffering (round-9: those collapse the B-in-registers
// allocation). 256 thr = 4 waves; wave w owns cols [32w,32w+32), B (hi+lo) in
// 64 VGPRs. Grid-stride over 16-row chunks (N = 6250*16 exact).
// Fragment maps (m89/m92): A[m=lane&15][k=quad*8+j], B[n=lane&15][k=quad*8+j],
// C/D col=lane&15, row=quad*4+reg.
__global__ void __launch_bounds__(256) k_gemm(
    const __bf16* __restrict__ X,
    const __bf16* __restrict__ Whi, const __bf16* __restrict__ Wlo,
    const float* __restrict__ bias,
    const float* __restrict__ sIn, const float* __restrict__ tIn, int applyIn,
    __bf16* __restrict__ Y,
    float* __restrict__ statpart) {
  int tid = threadIdx.x;
  int wave = tid >> 6;
  int lane = tid & 63;
  int n16 = lane & 15;
  int quad = lane >> 4;

  // load this wave's B fragments (2 col-tiles x 4 k-chunks, hi+lo)
  bf16x8 bhi[2][4];
  bf16x8 blo[2][4];
#pragma unroll
  for (int ct = 0; ct < 2; ++ct) {
    int n = (wave * 2 + ct) * 16 + n16;
#pragma unroll
    for (int kk = 0; kk < 4; ++kk) {
      int k0 = kk * 32 + quad * 8;
      bhi[ct][kk] = *(const bf16x8*)(Whi + (size_t)n * DMODEL + k0);
      blo[ct][kk] = *(const bf16x8*)(Wlo + (size_t)n * DMODEL + k0);
    }
  }
  float bc[2];
  bc[0] = bias[(wave * 2 + 0) * 16 + n16];
  bc[1] = bias[(wave * 2 + 1) * 16 + n16];

  float ssum[2] = {0.0f, 0.0f};
  float ssq[2] = {0.0f, 0.0f};

  const int NCHUNK = N_NODES / 16;   // 6250 exact
  for (int c = blockIdx.x; c < NCHUNK; c += gridDim.x) {
    int row0 = c * 16;
    bf16x8 a[4];
    {
      const __bf16* xr = X + (size_t)(row0 + n16) * DMODEL + quad * 8;
#pragma unroll
      for (int kk = 0; kk < 4; ++kk) a[kk] = *(const bf16x8*)(xr + kk * 32);
    }
    if (applyIn) {
#pragma unroll
      for (int kk = 0; kk < 4; ++kk) {
        int k0 = kk * 32 + quad * 8;
        float4 s0 = *(const float4*)(sIn + k0);
        float4 s1 = *(const float4*)(sIn + k0 + 4);
        float4 t0 = *(const float4*)(tIn + k0);
        float4 t1 = *(const float4*)(tIn + k0 + 4);
        float sv[8];
        float tv[8];
        sv[0] = s0.x; sv[1] = s0.y; sv[2] = s0.z; sv[3] = s0.w;
        sv[4] = s1.x; sv[5] = s1.y; sv[6] = s1.z; sv[7] = s1.w;
        tv[0] = t0.x; tv[1] = t0.y; tv[2] = t0.z; tv[3] = t0.w;
        tv[4] = t1.x; tv[5] = t1.y; tv[6] = t1.z; tv[7] = t1.w;
#pragma unroll
        for (int jj = 0; jj < 8; ++jj) {
          float f = (float)a[kk][jj];
          a[kk][jj] = (__bf16)fmaxf(sv[jj] * f + tv[jj], 0.0f);
        }
      }
    }

    f32x4 acc[2];
#pragma unroll
    for (int ct = 0; ct < 2; ++ct)
#pragma unroll
      for (int r = 0; r < 4; ++r) acc[ct][r] = 0.0f;

    // kk -> (hi, lo) order matches previous rounds (identical per-element rounding)
#pragma unroll
    for (int kk = 0; kk < 4; ++kk) {
#pragma unroll
      for (int ct = 0; ct < 2; ++ct) {
        acc[ct] = __builtin_amdgcn_mfma_f32_16x16x32_bf16(a[kk], bhi[ct][kk], acc[ct], 0, 0, 0);
        acc[ct] = __builtin_amdgcn_mfma_f32_16x16x32_bf16(a[kk], blo[ct][kk], acc[ct], 0, 0, 0);
      }
    }

    // epilogue: bias add, bf16 store, accumulate column stats in registers
#pragma unroll
    for (int ct = 0; ct < 2; ++ct) {
      int col = (wave * 2 + ct) * 16 + n16;
#pragma unroll
      for (int r = 0; r < 4; ++r) {
        int row = row0 + quad * 4 + r;
        float v = acc[ct][r] + bc[ct];
        Y[(size_t)row * DMODEL + col] = (__bf16)v;
        ssum[ct] += v;
        ssq[ct] += v * v;
      }
    }
  }

  // one reduction + atomic per (wave, ct) for the whole block
  int slot = blockIdx.x & (NSLOT - 1);
#pragma unroll
  for (int ct = 0; ct < 2; ++ct) {
    int col = (wave * 2 + ct) * 16 + n16;
    float s = ssum[ct];
    float q = ssq[ct];
    s += __shfl_xor(s, 16);
    q += __shfl_xor(q, 16);
    s += __shfl_xor(s, 32);
    q += __shfl_xor(q, 32);
    if (quad == 0) {
      atomicAdd(&statpart[slot * (2 * DMODEL) + col], s);
      atomicAdd(&statpart[slot * (2 * DMODEL) + DMODEL + col], q);
    }
  }
}

// ------- fold stat partials into BN scale/shift, and re-zero partials -------
__global__ void k_bnfin(float* __restrict__ statpart,
                        const float* __restrict__ gamma, const float* __restrict__ beta,
                        float* __restrict__ sOut, float* __restrict__ tOut) {
  int d = threadIdx.x;   // 128
  float sum = 0.0f;
  float sq = 0.0f;
  for (int p = 0; p < NSLOT; ++p) {
    sum += statpart[p * (2 * DMODEL) + d];
    sq  += statpart[p * (2 * DMODEL) + DMODEL + d];
  }
  float mean = sum * (1.0f / N_NODES);
  float var = sq * (1.0f / N_NODES) - mean * mean;
  float inv = rsqrtf(var + BN_EPS);
  float s = gamma[d] * inv;
  sOut[d] = s;
  tOut[d] = beta[d] - mean * s;
  for (int p = 0; p < NSLOT; ++p) {
    statpart[p * (2 * DMODEL) + d] = 0.0f;
    statpart[p * (2 * DMODEL) + DMODEL + d] = 0.0f;
  }
}

// ------- pooling partial sums of raw h (affine deferred to classifier) -------
__global__ void k_pool(const __bf16* __restrict__ h, const int* __restrict__ gstart,
                       float* __restrict__ psum) {
  int g = blockIdx.x;
  int slice = blockIdx.y;   // 0..7
  int lane = threadIdx.x;   // 64
  int d0 = lane * 2;
  int i0 = gstart[g];
  int i1 = gstart[g + 1];
  float a0 = 0.0f;
  float a1 = 0.0f;
  for (int i = i0 + slice; i < i1; i += 8) {
    bf16x2 v = *(const bf16x2*)(h + (size_t)i * DMODEL + d0);
    a0 += (float)v[0];
    a1 += (float)v[1];
  }
  atomicAdd(&psum[g * DMODEL + d0], a0);
  atomicAdd(&psum[g * DMODEL + d0 + 1], a1);
}

// ------- classifier: applies final BN affine + mean, then Linear-ReLU-Linear -------
__global__ void k_classifier(const float* __restrict__ psum, const int* __restrict__ gstart,
                             const float* __restrict__ s2, const float* __restrict__ t2,
                             const float* __restrict__ cw1, const float* __restrict__ cb1,
                             const float* __restrict__ cw2, const float* __restrict__ cb2,
                             float* __restrict__ out) {
  __shared__ float pl[DMODEL];
  __shared__ float hid[DMODEL];
  int g = blockIdx.x;
  int d = threadIdx.x;
  int cnt = gstart[g + 1] - gstart[g];
  pl[d] = (cnt > 0) ? (s2[d] * (psum[g * DMODEL + d] / (float)cnt) + t2[d]) : 0.0f;
  __syncthreads();
  float acc = cb1[d];
  for (int k = 0; k < DMODEL; ++k) acc += pl[k] * cw1[k * DMODEL + d];
  hid[d] = fmaxf(acc, 0.0f);
  __syncthreads();
  if (d < NCLASS) {
    float acc2 = cb2[d];
    for (int k = 0; k < DMODEL; ++k) acc2 += hid[k] * cw2[k * NCLASS + d];
    out[g * NCLASS + d] = acc2;
  }
}

// ---------------- launcher ----------------
extern "C" void kernel_launch(void* const* d_in, const int* in_sizes, int n_in,
                              void* d_out, int out_size, void* d_ws, size_t ws_size,
                              hipStream_t stream) {
  const int*   x      = (const int*)d_in[0];
  const int*   ei     = (const int*)d_in[1];
  const float* ea     = (const float*)d_in[2];
  const int*   batch  = (const int*)d_in[3];
  const float* emb    = (const float*)d_in[4];
  const float* edge_w = (const float*)d_in[5];
  const float* edge_b = (const float*)d_in[6];
  const float* w1     = (const float*)d_in[7];
  const float* b1     = (const float*)d_in[8];
  const float* g1     = (const float*)d_in[9];
  const float* beta1  = (const float*)d_in[10];
  const float* w2     = (const float*)d_in[11];
  const float* b2     = (const float*)d_in[12];
  const float* ng     = (const float*)d_in[13];
  const float* nb     = (const float*)d_in[14];
  const float* cw1    = (const float*)d_in[15];
  const float* cb1    = (const float*)d_in[16];
  const float* cw2    = (const float*)d_in[17];
  const float* cb2    = (const float*)d_in[18];

  char* ws = (char*)d_ws;
  size_t off = 0;
  auto alloc = [&](size_t bytes) -> void* {
    void* p = ws + off;
    off += (bytes + 255) & ~(size_t)255;
    return p;
  };

  __bf16* h_bf      = (__bf16*)alloc((size_t)N_NODES * DMODEL * sizeof(__bf16));
  __bf16* z_bf      = (__bf16*)alloc((size_t)N_NODES * DMODEL * sizeof(__bf16));
  __bf16* y1_bf     = (__bf16*)alloc((size_t)N_NODES * DMODEL * sizeof(__bf16));
  int*    row_start = (int*)alloc((N_NODES + 1) * sizeof(int));
  int*    cursor    = (int*)alloc(N_NODES * sizeof(int));
  int*    deg       = (int*)alloc(N_NODES * sizeof(int));
  int4*   epack     = (int4*)alloc((size_t)N_EDGES * sizeof(int4));
  __bf16* wt_hi     = (__bf16*)alloc((size_t)NLAYERS * 2 * DMODEL * DMODEL * sizeof(__bf16));
  __bf16* wt_lo     = (__bf16*)alloc((size_t)NLAYERS * 2 * DMODEL * DMODEL * sizeof(__bf16));
  float*  statpart  = (float*)alloc((size_t)NSLOT * 2 * DMODEL * sizeof(float));
  float*  st        = (float*)alloc((size_t)NLAYERS * 2 * 2 * DMODEL * sizeof(float));
  int*    gstart    = (int*)alloc((NGRAPH + 1) * sizeof(int));
  float*  psum      = (float*)alloc((size_t)NGRAPH * DMODEL * sizeof(float));
  int*    bsum      = (int*)alloc(512 * sizeof(int));
  int*    bsumx     = (int*)alloc(512 * sizeof(int));

  auto sArr = [&](int l, int which) { return st + ((l * 2 + which) * 2 + 0) * DMODEL; };
  auto tArr = [&](int l, int which) { return st + ((l * 2 + which) * 2 + 1) * DMODEL; };

  const int nbScan = (N_NODES + 255) / 256;              // 391
  const int nbEdge = (N_EDGES + 255) / 256;              // 2344
  const int nbEmb  = (N_NODES * DMODEL / 2 + 255) / 256; // 25000
  const int nbGemm = 1563;                               // grid-stride over 6250 chunks
  const int nbAgg  = N_NODES / 8;                        // 12500 (8 nodes/block)

  k_init<<<512, 256, 0, stream>>>(deg, statpart, psum,
                                  w1, w2, wt_hi, wt_lo, batch, gstart);
  k_embed<<<nbEmb, 256, 0, stream>>>(x, emb, h_bf);
  k_hist<<<nbEdge, 256, 0, stream>>>(ei + N_EDGES, deg);
  k_scan1<<<nbScan, 256, 0, stream>>>(deg, row_start, bsum, N_NODES);
  k_scan2<<<1, 512, 0, stream>>>(bsum, bsumx, nbScan);
  k_scan3<<<nbScan, 256, 0, stream>>>(row_start, cursor, bsumx, N_NODES, N_EDGES);
  k_scatter<<<nbEdge, 256, 0, stream>>>(ei, ea, cursor, epack);

  for (int l = 0; l < NLAYERS; ++l) {
    const float* sI = (l > 0) ? sArr(l - 1, 1) : (const float*)nullptr;
    const float* tI = (l > 0) ? tArr(l - 1, 1) : (const float*)nullptr;
    k_agg<<<nbAgg, 256, 0, stream>>>(h_bf, row_start, epack,
                                     edge_w + (size_t)l * 2 * DMODEL,
                                     edge_b + (size_t)l * DMODEL,
                                     sI, tI, (l > 0) ? 1 : 0, z_bf);
    // y1 = z @ w1[l] + b1[l]   (stats -> BN1)
    k_gemm<<<nbGemm, 256, 0, stream>>>(
        z_bf,
        wt_hi + (size_t)(l * 2 + 0) * DMODEL * DMODEL,
        wt_lo + (size_t)(l * 2 + 0) * DMODEL * DMODEL,
        b1 + (size_t)l * DMODEL,
        (const float*)nullptr, (const float*)nullptr, 0,
        y1_bf, statpart);
    k_bnfin<<<1, DMODEL, 0, stream>>>(statpart,
                                      g1 + (size_t)l * DMODEL, beta1 + (size_t)l * DMODEL,
                                      sArr(l, 0), tArr(l, 0));
    // h = relu(BN1(y1)) @ w2[l] + b2[l]   (stats -> BN2, applied by next consumer)
    k_gemm<<<nbGemm, 256, 0, stream>>>(
        y1_bf,
        wt_hi + (size_t)(l * 2 + 1) * DMODEL * DMODEL,
        wt_lo + (size_t)(l * 2 + 1) * DMODEL * DMODEL,
        b2 + (size_t)l * DMODEL,
        sArr(l, 0), tArr(l, 0), 1,
        h_bf, statpart);
    k_bnfin<<<1, DMODEL, 0, stream>>>(statpart,
                                      ng + (size_t)l * DMODEL, nb + (size_t)l * DMODEL,
                                      sArr(l, 1), tArr(l, 1));
  }

  dim3 poolGrid(NGRAPH, 8);
  k_pool<<<poolGrid, 64, 0, stream>>>(h_bf, gstart, psum);
  k_classifier<<<NGRAPH, DMODEL, 0, stream>>>(psum, gstart, sArr(NLAYERS - 1, 1),
                                              tArr(NLAYERS - 1, 1),
                                              cw1, cb1, cw2, cb2, (float*)d_out);
}

// Round 12
// 662.699 us; speedup vs baseline: 1.1311x; 1.1311x over previous
//
#include <hip/hip_runtime.h>
#include <stdint.h>

#define N_NODES 100000
#define N_EDGES 600000
#define DMODEL  128
#define NLAYERS 4
#define NGRAPH  128
#define NCLASS  10
#define BN_EPS  1e-5f
#define NSLOT   32     // stat partial slots (atomic contention spreading)

typedef __bf16 bf16x8 __attribute__((ext_vector_type(8)));
typedef __bf16 bf16x4 __attribute__((ext_vector_type(4)));
typedef __bf16 bf16x2 __attribute__((ext_vector_type(2)));
typedef float  f32x4  __attribute__((ext_vector_type(4)));

// ------- init: zero accumulators, transpose+split weights, graph boundaries -------
__global__ void k_init(int* __restrict__ deg, float* __restrict__ statA,
                       float* __restrict__ statB, float* __restrict__ psum,
                       const float* __restrict__ w1, const float* __restrict__ w2,
                       __bf16* __restrict__ wt_hi, __bf16* __restrict__ wt_lo,
                       const int* __restrict__ batch, int* __restrict__ gstart) {
  int i = blockIdx.x * 256 + threadIdx.x;   // grid 512*256 = 131072
  if (i < N_NODES) deg[i] = 0;
  if (i < NSLOT * 2 * DMODEL) {
    statA[i] = 0.0f;
    statB[i] = 0.0f;
  }
  if (i < NGRAPH * DMODEL) psum[i] = 0.0f;
  // weight transpose + hi/lo split: wt[mat][n][k] = split(w[mat][k][n])
  {
    int mat = i >> 14;
    int rem = i & 16383;
    int n = rem >> 7;
    int k = rem & 127;
    int l = mat >> 1;
    int which = mat & 1;
    const float* w = which ? w2 : w1;
    float v = w[(size_t)l * DMODEL * DMODEL + (size_t)k * DMODEL + n];
    __bf16 hi = (__bf16)v;
    wt_hi[i] = hi;
    wt_lo[i] = (__bf16)(v - (float)hi);
  }
  // graph boundaries by binary search over sorted batch
  if (i <= NGRAPH) {
    int lo = 0;
    int hi = N_NODES;
    while (lo < hi) {
      int mid = (lo + hi) >> 1;
      if (batch[mid] < i) lo = mid + 1; else hi = mid;
    }
    gstart[i] = lo;
  }
}

// ---------------- embedding gather: h[i,d] = bf16(emb[x[i],d]) ----------------
__global__ void k_embed(const int* __restrict__ x, const float* __restrict__ emb,
                        __bf16* __restrict__ h) {
  int idx = blockIdx.x * 256 + threadIdx.x;        // over N*D/2
  if (idx >= N_NODES * DMODEL / 2) return;
  int i = idx >> 6;
  int p = idx & 63;
  float2 v = *(const float2*)(emb + (size_t)x[i] * DMODEL + p * 2);
  bf16x2 o;
  o[0] = (__bf16)v.x;
  o[1] = (__bf16)v.y;
  *(bf16x2*)(h + (size_t)i * DMODEL + p * 2) = o;
}

// ---------------- CSR build ----------------
__global__ void k_hist(const int* __restrict__ dst, int* __restrict__ deg) {
  int e = blockIdx.x * 256 + threadIdx.x;
  if (e < N_EDGES) atomicAdd(&deg[dst[e]], 1);
}

__global__ void k_scan1(const int* __restrict__ deg, int* __restrict__ out,
                        int* __restrict__ bsum, int n) {
  __shared__ int lds[256];
  int t = threadIdx.x;
  int idx = blockIdx.x * 256 + t;
  int v = (idx < n) ? deg[idx] : 0;
  int val = v;
  lds[t] = val;
  for (int ofs = 1; ofs < 256; ofs <<= 1) {
    __syncthreads();
    int u = (t >= ofs) ? lds[t - ofs] : 0;
    __syncthreads();
    val += u;
    lds[t] = val;
  }
  if (idx < n) out[idx] = val - v;           // exclusive within chunk
  if (t == 255) bsum[blockIdx.x] = val;      // chunk total
}

__global__ void k_scan2(const int* __restrict__ bsum, int* __restrict__ bsumx, int nb) {
  __shared__ int lds[512];
  int t = threadIdx.x;
  int v = (t < nb) ? bsum[t] : 0;
  int val = v;
  lds[t] = val;
  for (int ofs = 1; ofs < 512; ofs <<= 1) {
    __syncthreads();
    int u = (t >= ofs) ? lds[t - ofs] : 0;
    __syncthreads();
    val += u;
    lds[t] = val;
  }
  if (t < nb) bsumx[t] = val - v;
}

__global__ void k_scan3(int* __restrict__ row_start, int* __restrict__ cursor,
                        const int* __restrict__ bsumx, int n, int total) {
  int idx = blockIdx.x * 256 + threadIdx.x;
  if (idx < n) {
    int v = row_start[idx] + bsumx[blockIdx.x];
    row_start[idx] = v;
    cursor[idx] = v;
  }
  if (idx == 0) row_start[n] = total;
}

// pack each edge as 16B {src, a0, a1, pad} at its CSR slot
__global__ void k_scatter(const int* __restrict__ ei, const float* __restrict__ ea,
                          int* __restrict__ cursor, int4* __restrict__ epack) {
  int e = blockIdx.x * 256 + threadIdx.x;
  if (e >= N_EDGES) return;
  int s = ei[e];
  int d = ei[N_EDGES + e];
  int pos = atomicAdd(&cursor[d], 1);
  int4 pk;
  pk.x = s;
  pk.y = __float_as_int(ea[2 * e]);
  pk.z = __float_as_int(ea[2 * e + 1]);
  pk.w = 0;
  epack[pos] = pk;
}

// ------- message + aggregate: z = act(h_i) + sum_in relu(act(h_src) + edge_lin) -----
// act(h) = relu(s*h + t) when hasT (deferred BN+relu of previous layer), else identity.
// HALF-WAVE per node: 32 lanes x 4 channels (bf16x4 8B gathers), 2 nodes/wave,
// 8 nodes/block. Measured at the ~55 us gather-latency floor (two arrangements tied).
__global__ void __launch_bounds__(256) k_agg(
    const __bf16* __restrict__ h, const int* __restrict__ row_start,
    const int4* __restrict__ epack,
    const float* __restrict__ ew,   // edge_w + l*2*D, layout [2][D]
    const float* __restrict__ ebp,  // edge_b + l*D
    const float* __restrict__ sIn, const float* __restrict__ tIn, int hasT,
    __bf16* __restrict__ z) {
  int node = blockIdx.x * 8 + (threadIdx.x >> 5);
  int ln = threadIdx.x & 31;
  int d0 = ln * 4;

  float4 ew0 = *(const float4*)(ew + d0);
  float4 ew1 = *(const float4*)(ew + DMODEL + d0);
  float4 eb  = *(const float4*)(ebp + d0);
  float4 s4;
  float4 t4;
  if (hasT) {
    s4 = *(const float4*)(sIn + d0);
    t4 = *(const float4*)(tIn + d0);
  }

  bf16x4 hv = *(const bf16x4*)(h + (size_t)node * DMODEL + d0);
  float acc0, acc1, acc2, acc3;
  {
    float r0 = (float)hv[0];
    float r1 = (float)hv[1];
    float r2 = (float)hv[2];
    float r3 = (float)hv[3];
    if (hasT) {
      acc0 = fmaxf(s4.x * r0 + t4.x, 0.0f);
      acc1 = fmaxf(s4.y * r1 + t4.y, 0.0f);
      acc2 = fmaxf(s4.z * r2 + t4.z, 0.0f);
      acc3 = fmaxf(s4.w * r3 + t4.w, 0.0f);
    } else {
      acc0 = r0; acc1 = r1; acc2 = r2; acc3 = r3;
    }
  }

  int j0 = row_start[node];
  int j1 = row_start[node + 1];
  int j = j0;

#define AGG_ONE(E, V)                                                          \
  {                                                                            \
    float a0 = __int_as_float((E).y);                                          \
    float a1 = __int_as_float((E).z);                                          \
    float f0 = (float)(V)[0];                                                  \
    float f1 = (float)(V)[1];                                                  \
    float f2 = (float)(V)[2];                                                  \
    float f3 = (float)(V)[3];                                                  \
    if (hasT) {                                                                \
      f0 = fmaxf(s4.x * f0 + t4.x, 0.0f);                                      \
      f1 = fmaxf(s4.y * f1 + t4.y, 0.0f);                                      \
      f2 = fmaxf(s4.z * f2 + t4.z, 0.0f);                                      \
      f3 = fmaxf(s4.w * f3 + t4.w, 0.0f);                                      \
    }                                                                          \
    acc0 += fmaxf(f0 + a0 * ew0.x + a1 * ew1.x + eb.x, 0.0f);                  \
    acc1 += fmaxf(f1 + a0 * ew0.y + a1 * ew1.y + eb.y, 0.0f);                  \
    acc2 += fmaxf(f2 + a0 * ew0.z + a1 * ew1.z + eb.z, 0.0f);                  \
    acc3 += fmaxf(f3 + a0 * ew0.w + a1 * ew1.w + eb.w, 0.0f);                  \
  }

  for (; j + 4 <= j1; j += 4) {
    int4 e0 = epack[j];
    int4 e1 = epack[j + 1];
    int4 e2 = epack[j + 2];
    int4 e3 = epack[j + 3];
    bf16x4 v0 = *(const bf16x4*)(h + (size_t)e0.x * DMODEL + d0);
    bf16x4 v1 = *(const bf16x4*)(h + (size_t)e1.x * DMODEL + d0);
    bf16x4 v2 = *(const bf16x4*)(h + (size_t)e2.x * DMODEL + d0);
    bf16x4 v3 = *(const bf16x4*)(h + (size_t)e3.x * DMODEL + d0);
    AGG_ONE(e0, v0)
    AGG_ONE(e1, v1)
    AGG_ONE(e2, v2)
    AGG_ONE(e3, v3)
  }
  for (; j < j1; ++j) {
    int4 e0 = epack[j];
    bf16x4 v0 = *(const bf16x4*)(h + (size_t)e0.x * DMODEL + d0);
    AGG_ONE(e0, v0)
  }
#undef AGG_ONE

  bf16x4 o;
  o[0] = (__bf16)acc0;
  o[1] = (__bf16)acc1;
  o[2] = (__bf16)acc2;
  o[3] = (__bf16)acc3;
  *(bf16x4*)(z + (size_t)node * DMODEL + d0) = o;
}

// ------- GEMM1: Y = X @ W + bias  (bf16 MFMA, split-W, register-B, 32-row chunks) ----
// ROUND-10 STRUCTURE VERBATIM (proven 703 us; 32-row chunks are the measured local
// optimum: 16-row/4-waves and LDS-tile variants are both slower). No barriers, no
// fences, no prefetch (round-9: those collapse the B-in-registers allocation).
// Fragment maps (m89/m92): A[m=lane&15][k=quad*8+j], B[n=lane&15][k=quad*8+j],
// C/D col=lane&15, row=quad*4+reg.
__global__ void __launch_bounds__(256) k_gemm1(
    const __bf16* __restrict__ X,
    const __bf16* __restrict__ Whi, const __bf16* __restrict__ Wlo,
    const float* __restrict__ bias,
    __bf16* __restrict__ Y,
    float* __restrict__ statpart) {
  int tid = threadIdx.x;
  int wave = tid >> 6;
  int lane = tid & 63;
  int n16 = lane & 15;
  int quad = lane >> 4;

  bf16x8 bhi[2][4];
  bf16x8 blo[2][4];
#pragma unroll
  for (int ct = 0; ct < 2; ++ct) {
    int n = (wave * 2 + ct) * 16 + n16;
#pragma unroll
    for (int kk = 0; kk < 4; ++kk) {
      int k0 = kk * 32 + quad * 8;
      bhi[ct][kk] = *(const bf16x8*)(Whi + (size_t)n * DMODEL + k0);
      blo[ct][kk] = *(const bf16x8*)(Wlo + (size_t)n * DMODEL + k0);
    }
  }
  float bc[2];
  bc[0] = bias[(wave * 2 + 0) * 16 + n16];
  bc[1] = bias[(wave * 2 + 1) * 16 + n16];

  float ssum[2] = {0.0f, 0.0f};
  float ssq[2] = {0.0f, 0.0f};

  const int NCHUNK = N_NODES / 32;   // 3125 exact
  for (int c = blockIdx.x; c < NCHUNK; c += gridDim.x) {
    int row0 = c * 32;
    bf16x8 a[2][4];
#pragma unroll
    for (int t = 0; t < 2; ++t) {
      const __bf16* xr = X + (size_t)(row0 + t * 16 + n16) * DMODEL;
#pragma unroll
      for (int kk = 0; kk < 4; ++kk) {
        a[t][kk] = *(const bf16x8*)(xr + kk * 32 + quad * 8);
      }
    }

    f32x4 acc[2][2];
#pragma unroll
    for (int t = 0; t < 2; ++t)
#pragma unroll
      for (int ct = 0; ct < 2; ++ct)
#pragma unroll
        for (int r = 0; r < 4; ++r) acc[t][ct][r] = 0.0f;

#pragma unroll
    for (int kk = 0; kk < 4; ++kk) {
#pragma unroll
      for (int ct = 0; ct < 2; ++ct) {
#pragma unroll
        for (int t = 0; t < 2; ++t) {
          acc[t][ct] = __builtin_amdgcn_mfma_f32_16x16x32_bf16(a[t][kk], bhi[ct][kk], acc[t][ct], 0, 0, 0);
          acc[t][ct] = __builtin_amdgcn_mfma_f32_16x16x32_bf16(a[t][kk], blo[ct][kk], acc[t][ct], 0, 0, 0);
        }
      }
    }

#pragma unroll
    for (int t = 0; t < 2; ++t) {
#pragma unroll
      for (int ct = 0; ct < 2; ++ct) {
        int col = (wave * 2 + ct) * 16 + n16;
#pragma unroll
        for (int r = 0; r < 4; ++r) {
          int row = row0 + t * 16 + quad * 4 + r;
          float v = acc[t][ct][r] + bc[ct];
          Y[(size_t)row * DMODEL + col] = (__bf16)v;
          ssum[ct] += v;
          ssq[ct] += v * v;
        }
      }
    }
  }

  int slot = blockIdx.x & (NSLOT - 1);
#pragma unroll
  for (int ct = 0; ct < 2; ++ct) {
    int col = (wave * 2 + ct) * 16 + n16;
    float s = ssum[ct];
    float q = ssq[ct];
    s += __shfl_xor(s, 16);
    q += __shfl_xor(q, 16);
    s += __shfl_xor(s, 32);
    q += __shfl_xor(q, 32);
    if (quad == 0) {
      atomicAdd(&statpart[slot * (2 * DMODEL) + col], s);
      atomicAdd(&statpart[slot * (2 * DMODEL) + DMODEL + col], q);
    }
  }
}

// ------- GEMM2: Y = relu(BN1(X)) @ W + bias, BN1 finalize fused into prologue ------
// Each block redundantly reduces statA (32 slots, L2-hot) into s/t in LDS BEFORE
// loading B fragments (single __syncthreads precedes the B live range — keeps the
// register-B allocation intact). K-loop identical to round-10 applyIn path but
// reads s/t from LDS. Reduction order matches k_bnfin -> bit-identical s/t.
__global__ void __launch_bounds__(256) k_gemm2(
    const __bf16* __restrict__ X,
    const __bf16* __restrict__ Whi, const __bf16* __restrict__ Wlo,
    const float* __restrict__ bias,
    const float* __restrict__ statA,
    const float* __restrict__ gamma, const float* __restrict__ beta,
    __bf16* __restrict__ Y,
    float* __restrict__ statpart) {
  __shared__ float sld[DMODEL];
  __shared__ float tld[DMODEL];
  int tid = threadIdx.x;

  if (tid < DMODEL) {
    float sum = 0.0f;
    float sq = 0.0f;
    for (int p = 0; p < NSLOT; ++p) {
      sum += statA[p * (2 * DMODEL) + tid];
      sq  += statA[p * (2 * DMODEL) + DMODEL + tid];
    }
    float mean = sum * (1.0f / N_NODES);
    float var = sq * (1.0f / N_NODES) - mean * mean;
    float inv = rsqrtf(var + BN_EPS);
    float s = gamma[tid] * inv;
    sld[tid] = s;
    tld[tid] = beta[tid] - mean * s;
  }
  __syncthreads();

  int wave = tid >> 6;
  int lane = tid & 63;
  int n16 = lane & 15;
  int quad = lane >> 4;

  bf16x8 bhi[2][4];
  bf16x8 blo[2][4];
#pragma unroll
  for (int ct = 0; ct < 2; ++ct) {
    int n = (wave * 2 + ct) * 16 + n16;
#pragma unroll
    for (int kk = 0; kk < 4; ++kk) {
      int k0 = kk * 32 + quad * 8;
      bhi[ct][kk] = *(const bf16x8*)(Whi + (size_t)n * DMODEL + k0);
      blo[ct][kk] = *(const bf16x8*)(Wlo + (size_t)n * DMODEL + k0);
    }
  }
  float bc[2];
  bc[0] = bias[(wave * 2 + 0) * 16 + n16];
  bc[1] = bias[(wave * 2 + 1) * 16 + n16];

  float ssum[2] = {0.0f, 0.0f};
  float ssq[2] = {0.0f, 0.0f};

  const int NCHUNK = N_NODES / 32;   // 3125 exact
  for (int c = blockIdx.x; c < NCHUNK; c += gridDim.x) {
    int row0 = c * 32;
    bf16x8 a[2][4];
#pragma unroll
    for (int t = 0; t < 2; ++t) {
      const __bf16* xr = X + (size_t)(row0 + t * 16 + n16) * DMODEL;
#pragma unroll
      for (int kk = 0; kk < 4; ++kk) {
        a[t][kk] = *(const bf16x8*)(xr + kk * 32 + quad * 8);
      }
    }
#pragma unroll
    for (int kk = 0; kk < 4; ++kk) {
      int k0 = kk * 32 + quad * 8;
      float4 s0 = *(const float4*)(sld + k0);
      float4 s1 = *(const float4*)(sld + k0 + 4);
      float4 t0 = *(const float4*)(tld + k0);
      float4 t1 = *(const float4*)(tld + k0 + 4);
      float sv[8];
      float tv[8];
      sv[0] = s0.x; sv[1] = s0.y; sv[2] = s0.z; sv[3] = s0.w;
      sv[4] = s1.x; sv[5] = s1.y; sv[6] = s1.z; sv[7] = s1.w;
      tv[0] = t0.x; tv[1] = t0.y; tv[2] = t0.z; tv[3] = t0.w;
      tv[4] = t1.x; tv[5] = t1.y; tv[6] = t1.z; tv[7] = t1.w;
#pragma unroll
      for (int t = 0; t < 2; ++t) {
#pragma unroll
        for (int jj = 0; jj < 8; ++jj) {
          float f = (float)a[t][kk][jj];
          a[t][kk][jj] = (__bf16)fmaxf(sv[jj] * f + tv[jj], 0.0f);
        }
      }
    }

    f32x4 acc[2][2];
#pragma unroll
    for (int t = 0; t < 2; ++t)
#pragma unroll
      for (int ct = 0; ct < 2; ++ct)
#pragma unroll
        for (int r = 0; r < 4; ++r) acc[t][ct][r] = 0.0f;

#pragma unroll
    for (int kk = 0; kk < 4; ++kk) {
#pragma unroll
      for (int ct = 0; ct < 2; ++ct) {
#pragma unroll
        for (int t = 0; t < 2; ++t) {
          acc[t][ct] = __builtin_amdgcn_mfma_f32_16x16x32_bf16(a[t][kk], bhi[ct][kk], acc[t][ct], 0, 0, 0);
          acc[t][ct] = __builtin_amdgcn_mfma_f32_16x16x32_bf16(a[t][kk], blo[ct][kk], acc[t][ct], 0, 0, 0);
        }
      }
    }

#pragma unroll
    for (int t = 0; t < 2; ++t) {
#pragma unroll
      for (int ct = 0; ct < 2; ++ct) {
        int col = (wave * 2 + ct) * 16 + n16;
#pragma unroll
        for (int r = 0; r < 4; ++r) {
          int row = row0 + t * 16 + quad * 4 + r;
          float v = acc[t][ct][r] + bc[ct];
          Y[(size_t)row * DMODEL + col] = (__bf16)v;
          ssum[ct] += v;
          ssq[ct] += v * v;
        }
      }
    }
  }

  int slot = blockIdx.x & (NSLOT - 1);
#pragma unroll
  for (int ct = 0; ct < 2; ++ct) {
    int col = (wave * 2 + ct) * 16 + n16;
    float s = ssum[ct];
    float q = ssq[ct];
    s += __shfl_xor(s, 16);
    q += __shfl_xor(q, 16);
    s += __shfl_xor(s, 32);
    q += __shfl_xor(q, 32);
    if (quad == 0) {
      atomicAdd(&statpart[slot * (2 * DMODEL) + col], s);
      atomicAdd(&statpart[slot * (2 * DMODEL) + DMODEL + col], q);
    }
  }
}

// ------- fold statB into BN2 scale/shift; re-zero BOTH stat buffers -------
__global__ void k_bnfin(float* __restrict__ statB, float* __restrict__ statA,
                        const float* __restrict__ gamma, const float* __restrict__ beta,
                        float* __restrict__ sOut, float* __restrict__ tOut) {
  int d = threadIdx.x;   // 128
  float sum = 0.0f;
  float sq = 0.0f;
  for (int p = 0; p < NSLOT; ++p) {
    sum += statB[p * (2 * DMODEL) + d];
    sq  += statB[p * (2 * DMODEL) + DMODEL + d];
  }
  float mean = sum * (1.0f / N_NODES);
  float var = sq * (1.0f / N_NODES) - mean * mean;
  float inv = rsqrtf(var + BN_EPS);
  float s = gamma[d] * inv;
  sOut[d] = s;
  tOut[d] = beta[d] - mean * s;
  for (int p = 0; p < NSLOT; ++p) {
    statB[p * (2 * DMODEL) + d] = 0.0f;
    statB[p * (2 * DMODEL) + DMODEL + d] = 0.0f;
    statA[p * (2 * DMODEL) + d] = 0.0f;
    statA[p * (2 * DMODEL) + DMODEL + d] = 0.0f;
  }
}

// ------- pooling partial sums of raw h (affine deferred to classifier) -------
__global__ void k_pool(const __bf16* __restrict__ h, const int* __restrict__ gstart,
                       float* __restrict__ psum) {
  int g = blockIdx.x;
  int slice = blockIdx.y;   // 0..7
  int lane = threadIdx.x;   // 64
  int d0 = lane * 2;
  int i0 = gstart[g];
  int i1 = gstart[g + 1];
  float a0 = 0.0f;
  float a1 = 0.0f;
  for (int i = i0 + slice; i < i1; i += 8) {
    bf16x2 v = *(const bf16x2*)(h + (size_t)i * DMODEL + d0);
    a0 += (float)v[0];
    a1 += (float)v[1];
  }
  atomicAdd(&psum[g * DMODEL + d0], a0);
  atomicAdd(&psum[g * DMODEL + d0 + 1], a1);
}

// ------- classifier: applies final BN affine + mean, then Linear-ReLU-Linear -------
__global__ void k_classifier(const float* __restrict__ psum, const int* __restrict__ gstart,
                             const float* __restrict__ s2, const float* __restrict__ t2,
                             const float* __restrict__ cw1, const float* __restrict__ cb1,
                             const float* __restrict__ cw2, const float* __restrict__ cb2,
                             float* __restrict__ out) {
  __shared__ float pl[DMODEL];
  __shared__ float hid[DMODEL];
  int g = blockIdx.x;
  int d = threadIdx.x;
  int cnt = gstart[g + 1] - gstart[g];
  pl[d] = (cnt > 0) ? (s2[d] * (psum[g * DMODEL + d] / (float)cnt) + t2[d]) : 0.0f;
  __syncthreads();
  float acc = cb1[d];
  for (int k = 0; k < DMODEL; ++k) acc += pl[k] * cw1[k * DMODEL + d];
  hid[d] = fmaxf(acc, 0.0f);
  __syncthreads();
  if (d < NCLASS) {
    float acc2 = cb2[d];
    for (int k = 0; k < DMODEL; ++k) acc2 += hid[k] * cw2[k * NCLASS + d];
    out[g * NCLASS + d] = acc2;
  }
}

// ---------------- launcher ----------------
extern "C" void kernel_launch(void* const* d_in, const int* in_sizes, int n_in,
                              void* d_out, int out_size, void* d_ws, size_t ws_size,
                              hipStream_t stream) {
  const int*   x      = (const int*)d_in[0];
  const int*   ei     = (const int*)d_in[1];
  const float* ea     = (const float*)d_in[2];
  const int*   batch  = (const int*)d_in[3];
  const float* emb    = (const float*)d_in[4];
  const float* edge_w = (const float*)d_in[5];
  const float* edge_b = (const float*)d_in[6];
  const float* w1     = (const float*)d_in[7];
  const float* b1     = (const float*)d_in[8];
  const float* g1     = (const float*)d_in[9];
  const float* beta1  = (const float*)d_in[10];
  const float* w2     = (const float*)d_in[11];
  const float* b2     = (const float*)d_in[12];
  const float* ng     = (const float*)d_in[13];
  const float* nb     = (const float*)d_in[14];
  const float* cw1    = (const float*)d_in[15];
  const float* cb1    = (const float*)d_in[16];
  const float* cw2    = (const float*)d_in[17];
  const float* cb2    = (const float*)d_in[18];

  char* ws = (char*)d_ws;
  size_t off = 0;
  auto alloc = [&](size_t bytes) -> void* {
    void* p = ws + off;
    off += (bytes + 255) & ~(size_t)255;
    return p;
  };

  __bf16* h_bf      = (__bf16*)alloc((size_t)N_NODES * DMODEL * sizeof(__bf16));
  __bf16* z_bf      = (__bf16*)alloc((size_t)N_NODES * DMODEL * sizeof(__bf16));
  __bf16* y1_bf     = (__bf16*)alloc((size_t)N_NODES * DMODEL * sizeof(__bf16));
  int*    row_start = (int*)alloc((N_NODES + 1) * sizeof(int));
  int*    cursor    = (int*)alloc(N_NODES * sizeof(int));
  int*    deg       = (int*)alloc(N_NODES * sizeof(int));
  int4*   epack     = (int4*)alloc((size_t)N_EDGES * sizeof(int4));
  __bf16* wt_hi     = (__bf16*)alloc((size_t)NLAYERS * 2 * DMODEL * DMODEL * sizeof(__bf16));
  __bf16* wt_lo     = (__bf16*)alloc((size_t)NLAYERS * 2 * DMODEL * DMODEL * sizeof(__bf16));
  float*  statA     = (float*)alloc((size_t)NSLOT * 2 * DMODEL * sizeof(float));
  float*  statB     = (float*)alloc((size_t)NSLOT * 2 * DMODEL * sizeof(float));
  float*  st        = (float*)alloc((size_t)NLAYERS * 2 * 2 * DMODEL * sizeof(float));
  int*    gstart    = (int*)alloc((NGRAPH + 1) * sizeof(int));
  float*  psum      = (float*)alloc((size_t)NGRAPH * DMODEL * sizeof(float));
  int*    bsum      = (int*)alloc(512 * sizeof(int));
  int*    bsumx     = (int*)alloc(512 * sizeof(int));

  auto sArr = [&](int l) { return st + (l * 2 + 0) * DMODEL; };
  auto tArr = [&](int l) { return st + (l * 2 + 1) * DMODEL; };

  const int nbScan = (N_NODES + 255) / 256;              // 391
  const int nbEdge = (N_EDGES + 255) / 256;              // 2344
  const int nbEmb  = (N_NODES * DMODEL / 2 + 255) / 256; // 25000
  const int nbGemm = 782;                                // grid-stride over 3125 chunks
  const int nbAgg  = N_NODES / 8;                        // 12500 (8 nodes/block)

  k_init<<<512, 256, 0, stream>>>(deg, statA, statB, psum,
                                  w1, w2, wt_hi, wt_lo, batch, gstart);
  k_embed<<<nbEmb, 256, 0, stream>>>(x, emb, h_bf);
  k_hist<<<nbEdge, 256, 0, stream>>>(ei + N_EDGES, deg);
  k_scan1<<<nbScan, 256, 0, stream>>>(deg, row_start, bsum, N_NODES);
  k_scan2<<<1, 512, 0, stream>>>(bsum, bsumx, nbScan);
  k_scan3<<<nbScan, 256, 0, stream>>>(row_start, cursor, bsumx, N_NODES, N_EDGES);
  k_scatter<<<nbEdge, 256, 0, stream>>>(ei, ea, cursor, epack);

  for (int l = 0; l < NLAYERS; ++l) {
    const float* sI = (l > 0) ? sArr(l - 1) : (const float*)nullptr;
    const float* tI = (l > 0) ? tArr(l - 1) : (const float*)nullptr;
    k_agg<<<nbAgg, 256, 0, stream>>>(h_bf, row_start, epack,
                                     edge_w + (size_t)l * 2 * DMODEL,
                                     edge_b + (size_t)l * DMODEL,
                                     sI, tI, (l > 0) ? 1 : 0, z_bf);
    // y1 = z @ w1[l] + b1[l]   (stats -> statA)
    k_gemm1<<<nbGemm, 256, 0, stream>>>(
        z_bf,
        wt_hi + (size_t)(l * 2 + 0) * DMODEL * DMODEL,
        wt_lo + (size_t)(l * 2 + 0) * DMODEL * DMODEL,
        b1 + (size_t)l * DMODEL,
        y1_bf, statA);
    // h = relu(BN1(y1)) @ w2[l] + b2[l]; BN1 finalize fused; stats -> statB
    k_gemm2<<<nbGemm, 256, 0, stream>>>(
        y1_bf,
        wt_hi + (size_t)(l * 2 + 1) * DMODEL * DMODEL,
        wt_lo + (size_t)(l * 2 + 1) * DMODEL * DMODEL,
        b2 + (size_t)l * DMODEL,
        statA, g1 + (size_t)l * DMODEL, beta1 + (size_t)l * DMODEL,
        h_bf, statB);
    // BN2 finalize -> s/t for next consumer; re-zero statA and statB
    k_bnfin<<<1, DMODEL, 0, stream>>>(statB, statA,
                                      ng + (size_t)l * DMODEL, nb + (size_t)l * DMODEL,
                                      sArr(l), tArr(l));
  }

  dim3 poolGrid(NGRAPH, 8);
  k_pool<<<poolGrid, 64, 0, stream>>>(h_bf, gstart, psum);
  k_classifier<<<NGRAPH, DMODEL, 0, stream>>>(psum, gstart, sArr(NLAYERS - 1),
                                              tArr(NLAYERS - 1),
                                              cw1, cb1, cw2, cb2, (float*)d_out);
}